// Round 4
// baseline (174.616 us; speedup 1.0000x reference)
//
#include <hip/hip_runtime.h>

// PopulationCoding fused kernel, round 4:
//   Diagnosis r3: LDS-read pipe (~55us) and VALU (~56us) BOTH near-saturated;
//   93us = poor overlap. Fix both sides of the GEMM:
//   - 2 rows x 8 cols per thread: 16 FMA per (32B B + 8B A) LDS read
//     -> B ds_read_b128 count halves vs r3 (LDS ~41us).
//   - 128-thread blocks, TM=32/TN=64/TK=64, grid 32x32=1024 blocks
//     -> 4 independent blocks/CU (8 waves/CU, 4 barrier groups interleave;
//        LDS 25.1KB/block, 4 fit in 160KB).
//   - A transposed [k][row] stride 34: row-pair fragment = one ds_read_b64,
//     8 unique even banks, broadcast, conflict-free.
// B=1024, IN=512, D=256, P=8, T=32. Output [1024,256] fp32.

constexpr int IN_DIM  = 512;
constexpr int D_DIM   = 256;
constexpr int NTOT    = 2048;   // D*P
constexpr int T_STEPS = 32;

constexpr int TM = 32;   // b-rows per block
constexpr int TN = 64;   // I-cols per block (= 8 d-groups)
constexpr int TK = 64;   // k-chunk

__global__ __launch_bounds__(128, 2)
void popcode_fused(const float* __restrict__ x,
                   const float* __restrict__ Wp,
                   const float* __restrict__ bp,
                   const float* __restrict__ thrs,
                   const float* __restrict__ rateW,
                   const float* __restrict__ rateB,
                   const float* __restrict__ c1w,
                   const float* __restrict__ c1b,
                   const float* __restrict__ c2w,
                   const float* __restrict__ c2b,
                   const float* __restrict__ fus,
                   float* __restrict__ out)
{
    // As [k][row] stride 34 (even -> b64-aligned row pairs; banks 2k+2rg,
    // 8 unique even banks per wave, 8-way broadcast, conflict-free reads).
    // Bs [k][col] stride 64: b128 reads 2-way bank-aliased (free).
    __shared__ float As[TK][TM + 2];
    __shared__ float Bs[TK][TN];

    const int tid = threadIdx.x;           // 0..127
    const int b0  = blockIdx.x * TM;
    const int c0  = blockIdx.y * TN;
    const int rg  = tid >> 3;              // 0..15 (row-pair index)
    const int dl  = tid & 7;               // 0..7  (d-group within tile)
    const int r2  = rg * 2;                // first of this thread's 2 rows

    float acc[2][8];
#pragma unroll
    for (int i = 0; i < 2; ++i)
#pragma unroll
        for (int j = 0; j < 8; ++j) acc[i][j] = 0.f;

    // ---------------- GEMM: I = x @ W_proj ----------------
    for (int kc = 0; kc < IN_DIM; kc += TK) {
        // stage A: 32x64 floats, 128 thr x 4 float4, transpose into LDS
#pragma unroll
        for (int i = 0; i < 4; ++i) {
            const int f   = tid + 128 * i;       // 0..511
            const int row = f >> 4;              // 0..31
            const int c4  = (f & 15) * 4;        // 0..60
            const float4 v =
                *reinterpret_cast<const float4*>(x + (b0 + row) * IN_DIM + kc + c4);
            As[c4 + 0][row] = v.x;
            As[c4 + 1][row] = v.y;
            As[c4 + 2][row] = v.z;
            As[c4 + 3][row] = v.w;
        }
        // stage B: 64x64 floats, 128 thr x 8 float4, row-major b128 writes
#pragma unroll
        for (int i = 0; i < 8; ++i) {
            const int f  = tid + 128 * i;        // 0..1023
            const int r  = f >> 4;               // 0..63
            const int c4 = (f & 15) * 4;
            *reinterpret_cast<float4*>(&Bs[r][c4]) =
                *reinterpret_cast<const float4*>(Wp + (kc + r) * NTOT + c0 + c4);
        }
        __syncthreads();

#pragma unroll 16
        for (int k = 0; k < TK; ++k) {
            const float2 a = *reinterpret_cast<const float2*>(&As[k][r2]);
            const float4 u = *reinterpret_cast<const float4*>(&Bs[k][dl * 8]);
            const float4 v = *reinterpret_cast<const float4*>(&Bs[k][dl * 8 + 4]);
            acc[0][0] += a.x * u.x;  acc[0][1] += a.x * u.y;
            acc[0][2] += a.x * u.z;  acc[0][3] += a.x * u.w;
            acc[0][4] += a.x * v.x;  acc[0][5] += a.x * v.y;
            acc[0][6] += a.x * v.z;  acc[0][7] += a.x * v.w;
            acc[1][0] += a.y * u.x;  acc[1][1] += a.y * u.y;
            acc[1][2] += a.y * u.z;  acc[1][3] += a.y * u.w;
            acc[1][4] += a.y * v.x;  acc[1][5] += a.y * v.y;
            acc[1][6] += a.y * v.z;  acc[1][7] += a.y * v.w;
        }
        __syncthreads();
    }

    // ---------------- uniform parameters (scalar/SGPR loads) --------------
    float thr[8], rw[8];
#pragma unroll
    for (int p = 0; p < 8; ++p) { thr[p] = thrs[p]; rw[p] = rateW[p]; }

    float w1[4][8][3], wb1[4], w2c[4];
#pragma unroll
    for (int c = 0; c < 4; ++c) {
        wb1[c] = c1b[c];
        w2c[c] = c2w[c];
#pragma unroll
        for (int p = 0; p < 8; ++p)
#pragma unroll
            for (int k = 0; k < 3; ++k)
                w1[c][p][k] = c1w[(c * 8 + p) * 3 + k];
    }
    const float rb_ = rateB[0];
    const float bb2 = c2b[0];
    const float f0 = fus[0], f1 = fus[1];
    const float fm = fmaxf(f0, f1);
    const float e0 = __expf(f0 - fm), e1 = __expf(f1 - fm);
    const float inv = 1.f / (e0 + e1);
    const float fw0 = e0 * inv, fw1 = e1 * inv;

    float bpv[8];
#pragma unroll
    for (int p = 0; p < 8; ++p) bpv[p] = bp[c0 + dl * 8 + p];

    // ---------------- per-(b,d): LIF -> rate + conv -> output -------------
#pragma unroll
    for (int bi = 0; bi < 2; ++bi) {
        float Iv[8], Imt[8], mem[8];
        unsigned swv[8];
        bool spk[8];
#pragma unroll
        for (int p = 0; p < 8; ++p) {
            Iv[p]  = acc[bi][p] + bpv[p];
            Imt[p] = Iv[p] - thr[p];   // I - thr (used when reset fires)
            mem[p] = 0.f;
            swv[p] = 0u;
            spk[p] = false;
        }

        // LIF: reset_t = spk_{t-1}; mem = beta*mem + I - reset*thr; spk = mem>thr
        for (int t = 0; t < T_STEPS; ++t) {
            const unsigned bit = 1u << t;
#pragma unroll
            for (int p = 0; p < 8; ++p) {
                mem[p] = 0.95f * mem[p] + (spk[p] ? Imt[p] : Iv[p]);
                spk[p] = mem[p] > thr[p];
                swv[p] |= spk[p] ? bit : 0u;
            }
        }

        // rate branch: popcount/32 dot rate_W
        float rsum = 0.f;
#pragma unroll
        for (int p = 0; p < 8; ++p) rsum += (float)__popc(swv[p]) * rw[p];
        const float rdec = rsum * (1.f / 32.f) + rb_;

        // temporal branch: conv1(P->4,K=3,SAME) -> relu -> conv2(4->1,K=1) -> mean_t
        float svp[8], svc[8], svn[8];
#pragma unroll
        for (int p = 0; p < 8; ++p) {
            svp[p] = 0.f;
            svc[p] = (float)(swv[p] & 1u);
        }
        float tacc = 0.f;
#pragma unroll 4
        for (int t = 0; t < T_STEPS; ++t) {
#pragma unroll
            for (int p = 0; p < 8; ++p)
                svn[p] = (t < 31) ? (float)((swv[p] >> (t + 1)) & 1u) : 0.f;
#pragma unroll
            for (int c = 0; c < 4; ++c) {
                float h = wb1[c];
#pragma unroll
                for (int p = 0; p < 8; ++p) {
                    h = fmaf(w1[c][p][0], svp[p], h);
                    h = fmaf(w1[c][p][1], svc[p], h);
                    h = fmaf(w1[c][p][2], svn[p], h);
                }
                tacc = fmaf(fmaxf(h, 0.f), w2c[c], tacc);
            }
#pragma unroll
            for (int p = 0; p < 8; ++p) { svp[p] = svc[p]; svc[p] = svn[p]; }
        }
        const float temp = tacc * (1.f / 32.f) + bb2;

        out[(b0 + r2 + bi) * D_DIM + (c0 >> 3) + dl] = fw0 * rdec + fw1 * temp;
    }
}

extern "C" void kernel_launch(void* const* d_in, const int* in_sizes, int n_in,
                              void* d_out, int out_size, void* d_ws, size_t ws_size,
                              hipStream_t stream) {
    const float* x     = (const float*)d_in[0];
    const float* Wp    = (const float*)d_in[1];
    const float* bp    = (const float*)d_in[2];
    const float* thrs  = (const float*)d_in[3];
    const float* rateW = (const float*)d_in[4];
    const float* rateB = (const float*)d_in[5];
    const float* c1w   = (const float*)d_in[6];
    const float* c1b   = (const float*)d_in[7];
    const float* c2w   = (const float*)d_in[8];
    const float* c2b   = (const float*)d_in[9];
    const float* fus   = (const float*)d_in[10];
    float* out = (float*)d_out;

    dim3 grid(1024 / TM, 2048 / TN);   // 32 x 32 = 1024 blocks (4/CU)
    popcode_fused<<<grid, dim3(128), 0, stream>>>(
        x, Wp, bp, thrs, rateW, rateB, c1w, c1b, c2w, c2b, fus, out);
}

// Round 5
// 154.451 us; speedup vs baseline: 1.1306x; 1.1306x over previous
//
#include <hip/hip_runtime.h>

// PopulationCoding, round 5: SPLIT kernels through d_ws.
//   Evidence r1-r4: dur tracks waves/CU; fused kernel capped at 16 waves/CU
//   by 33KB LDS + 512-block grid, VALUBusy <=62%. Epilogue (~60% of VALU
//   work) needs no LDS -> split it out at full grid occupancy.
//   K1: r1's 52-VGPR GEMM structure + k-split 2 (grid.z) -> 1024 blocks,
//       4 blk/CU x 4 waves = 16 waves/CU. Partial I -> d_ws (2 x 8 MB).
//   K2: 1 thread per (b,d), no LDS/barriers, conv weights in SGPRs,
//       1024 blocks x 256 thr = 16 waves/CU, pure VALU issue.
// B=1024, IN=512, D=256, P=8, T=32. Output [1024,256] fp32.

constexpr int IN_DIM  = 512;
constexpr int D_DIM   = 256;
constexpr int NTOT    = 2048;   // D*P
constexpr int T_STEPS = 32;

constexpr int TM = 64;
constexpr int TN = 64;
constexpr int TK = 64;

// ---------------------------------------------------------------- K1: GEMM
__global__ __launch_bounds__(256)
void popcode_gemm(const float* __restrict__ x,
                  const float* __restrict__ Wp,
                  float* __restrict__ ws,    // [nsplit][1024][2048] partial I
                  int ksplit)                // K elems per z-slice
{
    __shared__ float As[TK][TM + 2];   // [k][row], stride 66 (8B-aligned pairs)
    __shared__ float Bs[TK][TN];

    const int tid = threadIdx.x;
    const int b0  = blockIdx.x * TM;
    const int c0  = blockIdx.y * TN;
    const int k0  = blockIdx.z * ksplit;
    const int rg  = tid >> 3;      // 0..31
    const int dl  = tid & 7;       // 0..7
    const int r2  = rg * 2;

    float acc[2][8];
#pragma unroll
    for (int i = 0; i < 2; ++i)
#pragma unroll
        for (int j = 0; j < 8; ++j) acc[i][j] = 0.f;

    for (int kc = k0; kc < k0 + ksplit; kc += TK) {
#pragma unroll
        for (int i = 0; i < 4; ++i) {
            const int f   = tid + 256 * i;       // 0..1023
            const int row = f >> 4;              // 0..63
            const int c4  = (f & 15) * 4;        // 0..60
            const float4 v =
                *reinterpret_cast<const float4*>(x + (b0 + row) * IN_DIM + kc + c4);
            As[c4 + 0][row] = v.x;
            As[c4 + 1][row] = v.y;
            As[c4 + 2][row] = v.z;
            As[c4 + 3][row] = v.w;
        }
#pragma unroll
        for (int i = 0; i < 4; ++i) {
            const int f  = tid + 256 * i;
            const int r  = f >> 4;
            const int c4 = (f & 15) * 4;
            *reinterpret_cast<float4*>(&Bs[r][c4]) =
                *reinterpret_cast<const float4*>(Wp + (kc + r) * NTOT + c0 + c4);
        }
        __syncthreads();

#pragma unroll 16
        for (int k = 0; k < TK; ++k) {
            const float2 a = *reinterpret_cast<const float2*>(&As[k][r2]);
            const float4 u = *reinterpret_cast<const float4*>(&Bs[k][dl * 8]);
            const float4 v = *reinterpret_cast<const float4*>(&Bs[k][dl * 8 + 4]);
            acc[0][0] += a.x * u.x;  acc[0][1] += a.x * u.y;
            acc[0][2] += a.x * u.z;  acc[0][3] += a.x * u.w;
            acc[0][4] += a.x * v.x;  acc[0][5] += a.x * v.y;
            acc[0][6] += a.x * v.z;  acc[0][7] += a.x * v.w;
            acc[1][0] += a.y * u.x;  acc[1][1] += a.y * u.y;
            acc[1][2] += a.y * u.z;  acc[1][3] += a.y * u.w;
            acc[1][4] += a.y * v.x;  acc[1][5] += a.y * v.y;
            acc[1][6] += a.y * v.z;  acc[1][7] += a.y * v.w;
        }
        __syncthreads();
    }

    // write partial I: rows r2,r2+1, cols c0+dl*8 .. +8 (two float4 each)
    float* dst = ws + (size_t)blockIdx.z * 1024 * NTOT;
#pragma unroll
    for (int bi = 0; bi < 2; ++bi) {
        float* p = dst + (size_t)(b0 + r2 + bi) * NTOT + c0 + dl * 8;
        float4 lo = {acc[bi][0], acc[bi][1], acc[bi][2], acc[bi][3]};
        float4 hi = {acc[bi][4], acc[bi][5], acc[bi][6], acc[bi][7]};
        *reinterpret_cast<float4*>(p)     = lo;
        *reinterpret_cast<float4*>(p + 4) = hi;
    }
}

// ------------------------------------------------------------ K2: epilogue
__global__ __launch_bounds__(256)
void popcode_epi(const float* __restrict__ ws,
                 const float* __restrict__ bp,
                 const float* __restrict__ thrs,
                 const float* __restrict__ rateW,
                 const float* __restrict__ rateB,
                 const float* __restrict__ c1w,
                 const float* __restrict__ c1b,
                 const float* __restrict__ c2w,
                 const float* __restrict__ c2b,
                 const float* __restrict__ fus,
                 float* __restrict__ out,
                 int nsplit)
{
    const int g = blockIdx.x * 256 + threadIdx.x;   // 0..262143
    const int b = g >> 8;
    const int d = g & 255;

    // ---- uniform parameters: scalar loads -> SGPRs ----
    float thr[8], rw[8];
#pragma unroll
    for (int p = 0; p < 8; ++p) { thr[p] = thrs[p]; rw[p] = rateW[p]; }

    float w1[4][8][3], wb1[4], w2c[4];
#pragma unroll
    for (int c = 0; c < 4; ++c) {
        wb1[c] = c1b[c];
        w2c[c] = c2w[c];
#pragma unroll
        for (int p = 0; p < 8; ++p)
#pragma unroll
            for (int k = 0; k < 3; ++k)
                w1[c][p][k] = c1w[(c * 8 + p) * 3 + k];
    }
    const float rb_ = rateB[0];
    const float bb2 = c2b[0];
    const float f0 = fus[0], f1 = fus[1];
    const float fm = fmaxf(f0, f1);
    const float e0 = __expf(f0 - fm), e1 = __expf(f1 - fm);
    const float inv = 1.f / (e0 + e1);
    const float fw0 = e0 * inv, fw1 = e1 * inv;

    // ---- gather I for this (b,d): sum partials ----
    const size_t base = (size_t)b * NTOT + d * 8;
    float4 lo = *reinterpret_cast<const float4*>(ws + base);
    float4 hi = *reinterpret_cast<const float4*>(ws + base + 4);
    if (nsplit == 2) {
        const float4 l1 = *reinterpret_cast<const float4*>(ws + 1024 * (size_t)NTOT + base);
        const float4 h1 = *reinterpret_cast<const float4*>(ws + 1024 * (size_t)NTOT + base + 4);
        lo.x += l1.x; lo.y += l1.y; lo.z += l1.z; lo.w += l1.w;
        hi.x += h1.x; hi.y += h1.y; hi.z += h1.z; hi.w += h1.w;
    }
    float Iv[8] = {lo.x, lo.y, lo.z, lo.w, hi.x, hi.y, hi.z, hi.w};

    float Imt[8], mem[8];
    unsigned swv[8];
    bool spk[8];
#pragma unroll
    for (int p = 0; p < 8; ++p) {
        Iv[p] += bp[d * 8 + p];
        Imt[p] = Iv[p] - thr[p];
        mem[p] = 0.f;
        swv[p] = 0u;
        spk[p] = false;
    }

    // LIF: reset_t = spk_{t-1}; mem = beta*mem + I - reset*thr; spk = mem>thr
#pragma unroll 8
    for (int t = 0; t < T_STEPS; ++t) {
        const unsigned bit = 1u << t;
#pragma unroll
        for (int p = 0; p < 8; ++p) {
            mem[p] = 0.95f * mem[p] + (spk[p] ? Imt[p] : Iv[p]);
            spk[p] = mem[p] > thr[p];
            swv[p] |= spk[p] ? bit : 0u;
        }
    }

    // rate branch
    float rsum = 0.f;
#pragma unroll
    for (int p = 0; p < 8; ++p) rsum += (float)__popc(swv[p]) * rw[p];
    const float rdec = rsum * (1.f / 32.f) + rb_;

    // temporal branch: conv1(P->4,K=3,SAME) -> relu -> conv2 -> mean_t
    float svp[8], svc[8], svn[8];
#pragma unroll
    for (int p = 0; p < 8; ++p) {
        svp[p] = 0.f;
        svc[p] = (float)(swv[p] & 1u);
    }
    float tacc = 0.f;
#pragma unroll 8
    for (int t = 0; t < T_STEPS; ++t) {
#pragma unroll
        for (int p = 0; p < 8; ++p)
            svn[p] = (t < 31) ? (float)((swv[p] >> (t + 1)) & 1u) : 0.f;
#pragma unroll
        for (int c = 0; c < 4; ++c) {
            float h = wb1[c];
#pragma unroll
            for (int p = 0; p < 8; ++p) {
                h = fmaf(w1[c][p][0], svp[p], h);
                h = fmaf(w1[c][p][1], svc[p], h);
                h = fmaf(w1[c][p][2], svn[p], h);
            }
            tacc = fmaf(fmaxf(h, 0.f), w2c[c], tacc);
        }
#pragma unroll
        for (int p = 0; p < 8; ++p) { svp[p] = svc[p]; svc[p] = svn[p]; }
    }
    const float temp = tacc * (1.f / 32.f) + bb2;

    out[b * D_DIM + d] = fw0 * rdec + fw1 * temp;
}

extern "C" void kernel_launch(void* const* d_in, const int* in_sizes, int n_in,
                              void* d_out, int out_size, void* d_ws, size_t ws_size,
                              hipStream_t stream) {
    const float* x     = (const float*)d_in[0];
    const float* Wp    = (const float*)d_in[1];
    const float* bp    = (const float*)d_in[2];
    const float* thrs  = (const float*)d_in[3];
    const float* rateW = (const float*)d_in[4];
    const float* rateB = (const float*)d_in[5];
    const float* c1w   = (const float*)d_in[6];
    const float* c1b   = (const float*)d_in[7];
    const float* c2w   = (const float*)d_in[8];
    const float* c2b   = (const float*)d_in[9];
    const float* fus   = (const float*)d_in[10];
    float* out = (float*)d_out;
    float* ws  = (float*)d_ws;

    // k-split 2 needs 16 MB of ws; fall back to 1 slice (8 MB) if tight.
    const size_t slice = (size_t)1024 * NTOT * sizeof(float);
    const int nsplit = (ws_size >= 2 * slice) ? 2 : 1;

    dim3 g1(1024 / TM, NTOT / TN, nsplit);   // 16 x 32 x nsplit
    popcode_gemm<<<g1, dim3(256), 0, stream>>>(x, Wp, ws, IN_DIM / nsplit);

    popcode_epi<<<dim3(1024), dim3(256), 0, stream>>>(
        ws, bp, thrs, rateW, rateB, c1w, c1b, c2w, c2b, fus, out, nsplit);
}